// Round 15
// baseline (38.661 us; speedup 1.0000x reference)
//
#include <hip/hip_runtime.h>

#define HH 48
#define WWD 48
#define CC 256
#define OCC 256
#define NPIX 2304
#define NB 2
#define NHEADS 4
#define DHEAD 64
#define SCALE_E 0.1803368802f   // 0.125 * log2(e); softmax via exp2

// attention tiling: 2x16 pixel tile, 6x20 patch
#define TH 2
#define TW 16
#define PHR 6
#define PWC 20
#define NPOS 120            // PHR*PWC
#define NTILES 72           // (48/2)*(48/16)

#define SLAB ((size_t)NPIX * OCC)   // elements (fp16 ushort)
#define WQN (256 * 256)             // elements per W matrix

typedef __attribute__((ext_vector_type(8))) short short8v;
typedef __attribute__((ext_vector_type(4))) float floatx4;
typedef _Float16 half2v __attribute__((ext_vector_type(2)));
typedef __fp16 fp16x2 __attribute__((ext_vector_type(2)));
union h2u { unsigned u; half2v h; fp16x2 g; };

__device__ __forceinline__ unsigned short f2bf(float f) {
    union { float f; unsigned u; } v; v.f = f;
    unsigned r = v.u + 0x7FFFu + ((v.u >> 16) & 1u);   // RNE
    return (unsigned short)(r >> 16);
}
__device__ __forceinline__ float bf2f(unsigned short b) {
    union { unsigned u; float f; } v; v.u = ((unsigned)b) << 16; return v.f;
}
__device__ __forceinline__ unsigned cvt_pk_bf16(float a, float b) {
    unsigned r;
    asm("v_cvt_pk_bf16_f32 %0, %1, %2" : "=v"(r) : "v"(a), "v"(b));
    return r;   // lo = bf16(a), hi = bf16(b)
}

// 8-lane (bits 0..2) all-reduce sum: xor1/xor2 via DPP quad_perm (VALU pipe),
// xor4 via one shfl.
__device__ __forceinline__ float xreduce8(float s) {
    s += __int_as_float(__builtin_amdgcn_update_dpp(
        0, __float_as_int(s), 0xB1, 0xf, 0xf, true));   // [1,0,3,2]
    s += __int_as_float(__builtin_amdgcn_update_dpp(
        0, __float_as_int(s), 0x4E, 0xf, 0xf, true));   // [2,3,0,1]
    s += __shfl_xor(s, 4, 64);
    return s;
}

// ---------------------------------------------------------------------------
// One-time W pre-conversion: Wq/Wkv fp32 [o][c] -> hi/lo bf16 slabs in ws.
// Removes ~640 redundant VALU/thread of per-block conversion from proj_mfma
// (W was being re-converted by all 144 blocks sharing each o-panel).
// ---------------------------------------------------------------------------
__global__ __launch_bounds__(256) void prep_w(
    const float* __restrict__ Wq, const float* __restrict__ Wkv,
    unsigned short* __restrict__ wsW)
{
    const int g = blockIdx.x * 256 + threadIdx.x;   // 0..16383
    const int mat = g >> 13;                        // 0: Wq, 1: Wkv
    const int i = (g & 8191) * 8;
    const float* W = mat ? Wkv : Wq;
    unsigned short* hi = wsW + (size_t)mat * 2 * WQN;
    unsigned short* lo = hi + WQN;

    float4 a = *reinterpret_cast<const float4*>(&W[i]);
    float4 b = *reinterpret_cast<const float4*>(&W[i + 4]);
    const float v[8] = {a.x, a.y, a.z, a.w, b.x, b.y, b.z, b.w};
    unsigned short hv[8], lv[8];
#pragma unroll
    for (int k = 0; k < 8; ++k) {
        hv[k] = f2bf(v[k]);
        lv[k] = f2bf(v[k] - bf2f(hv[k]));
    }
    *reinterpret_cast<ushort4*>(&hi[i]) = make_ushort4(hv[0], hv[1], hv[2], hv[3]);
    *reinterpret_cast<ushort4*>(&hi[i + 4]) = make_ushort4(hv[4], hv[5], hv[6], hv[7]);
    *reinterpret_cast<ushort4*>(&lo[i]) = make_ushort4(lv[0], lv[1], lv[2], lv[3]);
    *reinterpret_cast<ushort4*>(&lo[i + 4]) = make_ushort4(lv[4], lv[5], lv[6], lv[7]);
}

// ---------------------------------------------------------------------------
// MFMA projection: out[x][o] = sum_c W[o][c]*X[c][x].
// A = W hi/lo bf16 loaded pre-converted from ws (pure 16B loads, L2-hot).
// B = X^T staged to LDS as bf16 via in-register 4x4 transpose; conversion by
// v_cvt_pk_bf16_f32 (1 instr / 2 values vs 4/value manual RNE).
// Output slabs stored FP16 (cvt_pkrtz; RTZ@10-bit mantissa is more precise
// than RNE@bf16 -> error budget improves) for attn's fdot2 consumption.
// ---------------------------------------------------------------------------
__global__ __launch_bounds__(256) void proj_mfma(
    const float* __restrict__ qmap, const float* __restrict__ kv1,
    const float* __restrict__ kv2, const unsigned short* __restrict__ wsW,
    unsigned short* __restrict__ ws)
{
    __shared__ unsigned short Bs[64 * 64];   // 8 KB, [x][k] bf16 swizzled

    const int z = blockIdx.z;
    const int map = z % 3;
    const int b = z / 3;
    const float* X = ((map == 0) ? qmap : (map == 1) ? kv1 : kv2)
                     + (size_t)b * CC * NPIX;
    const unsigned short* Whi = wsW + (size_t)(map == 0 ? 0 : 1) * 2 * WQN;
    const unsigned short* Wlo = Whi + WQN;
    unsigned short* out = ws + ((size_t)map * NB + b) * SLAB;

    const int tid = threadIdx.x;
    const int x0 = blockIdx.x * 64;
    const int o0 = blockIdx.y * 64;
    const int lane = tid & 63;
    const int wv = tid >> 6;
    const int l15 = lane & 15;
    const int l4 = lane >> 4;
    const int kq_w = tid >> 4;
    const int xq = tid & 15;

    const int arowO = o0 + wv * 16 + l15;

    floatx4 acc[4];
#pragma unroll
    for (int nt = 0; nt < 4; ++nt) acc[nt] = (floatx4){0.f, 0.f, 0.f, 0.f};

#pragma unroll
    for (int kt = 0; kt < 4; ++kt) {
        const int k0t = kt * 64;
        const int abase = arowO * CC + k0t + l4 * 8;

        // A fragments: pre-converted hi/lo bf16, direct 16B loads
        short8v ah0 = *reinterpret_cast<const short8v*>(Whi + abase);
        short8v al0 = *reinterpret_cast<const short8v*>(Wlo + abase);
        short8v ah1 = *reinterpret_cast<const short8v*>(Whi + abase + 32);
        short8v al1 = *reinterpret_cast<const short8v*>(Wlo + abase + 32);

        // B stage: 4x4 in-register transpose, cvt_pk bf16, 8B swizzled writes
        float4 xv[4];
#pragma unroll
        for (int i = 0; i < 4; ++i)
            xv[i] = *reinterpret_cast<const float4*>(
                &X[(size_t)(k0t + kq_w * 4 + i) * NPIX + x0 + xq * 4]);
        {
            float xt[4][4] = {
                {xv[0].x, xv[1].x, xv[2].x, xv[3].x},
                {xv[0].y, xv[1].y, xv[2].y, xv[3].y},
                {xv[0].z, xv[1].z, xv[2].z, xv[3].z},
                {xv[0].w, xv[1].w, xv[2].w, xv[3].w}};
#pragma unroll
            for (int j = 0; j < 4; ++j) {
                const int x = xq * 4 + j;
                const unsigned w0 = cvt_pk_bf16(xt[j][0], xt[j][1]);
                const unsigned w1 = cvt_pk_bf16(xt[j][2], xt[j][3]);
                *reinterpret_cast<uint2*>(
                    (char*)Bs + x * 128 + ((kq_w ^ (x & 15)) << 3)) =
                    make_uint2(w0, w1);
            }
        }
        __syncthreads();

#pragma unroll
        for (int kc = 0; kc < 2; ++kc) {
            const short8v ah = kc ? ah1 : ah0;
            const short8v al = kc ? al1 : al0;
#pragma unroll
            for (int nt = 0; nt < 4; ++nt) {
                const int x = nt * 16 + l15;
                const int kq = kc * 8 + l4 * 2;
                ushort4 b0 = *reinterpret_cast<ushort4*>(
                    (char*)Bs + x * 128 + ((kq ^ l15) << 3));
                ushort4 b1 = *reinterpret_cast<ushort4*>(
                    (char*)Bs + x * 128 + (((kq + 1) ^ l15) << 3));
                short8v bh;
                bh[0] = (short)b0.x; bh[1] = (short)b0.y;
                bh[2] = (short)b0.z; bh[3] = (short)b0.w;
                bh[4] = (short)b1.x; bh[5] = (short)b1.y;
                bh[6] = (short)b1.z; bh[7] = (short)b1.w;
                acc[nt] = __builtin_amdgcn_mfma_f32_16x16x32_bf16(ah, bh, acc[nt], 0, 0, 0);
                acc[nt] = __builtin_amdgcn_mfma_f32_16x16x32_bf16(al, bh, acc[nt], 0, 0, 0);
            }
        }
        __syncthreads();
    }

    // fp16 epilogue: lane covers (x, 4 consecutive o) -> one 8B store
#pragma unroll
    for (int nt = 0; nt < 4; ++nt) {
        const int x = nt * 16 + l15;
        h2u p0, p1;
        p0.g = __builtin_amdgcn_cvt_pkrtz(acc[nt][0], acc[nt][1]);
        p1.g = __builtin_amdgcn_cvt_pkrtz(acc[nt][2], acc[nt][3]);
        *reinterpret_cast<uint2*>(
            &out[(size_t)(x0 + x) * OCC + o0 + wv * 16 + l4 * 4]) =
            make_uint2(p0.u, p1.u);
    }
}

// ---------------------------------------------------------------------------
// Attention (R12 structure, fp16 + fdot2): 256-thread (4-wave) blocks; block
// = 2x16 pixel tile for one (b, head). tid = pixl*8 + e; thread handles BOTH
// maps. fp16 slabs -> staging is pure 16B copies (pre-swizzled source unit).
// Dot via v_dot2_f32_f16 (f32 accumulate, 8 instr vs 16 unpack + 16 FMA);
// unpack (cvt_f32_f16) only feeds the p*k accumulation. No-max exp2 softmax;
// 8-lane reduce = 2 DPP + 1 shfl. XCD-bijective block swizzle: each XCD gets
// all 72 tiles of one (b,head) -> overlapping k-patches stay in its L2.
// __launch_bounds__(256,4): VGPR<=128, no spill (R11 lesson).
// ---------------------------------------------------------------------------
__global__ __launch_bounds__(256, 4) void attn_kernel(
    const unsigned short* __restrict__ ws, float* __restrict__ out)
{
    __shared__ __align__(16) unsigned short kp[2 * NPOS * 64];   // 30720 B

    const int tid = threadIdx.x;
    const int bid0 = blockIdx.x;                   // 576 = 8 * 72
    const int bid = (bid0 & 7) * 72 + (bid0 >> 3); // XCD-bijective swizzle
    const int tile = bid % NTILES;
    const int head = (bid / NTILES) % NHEADS;
    const int b = bid / (NTILES * NHEADS);
    const int h0 = (tile / 3) * TH;
    const int w0 = (tile % 3) * TW;

    const unsigned short* qp = ws + (size_t)(0 * NB + b) * SLAB;
    const unsigned short* k1 = ws + (size_t)(1 * NB + b) * SLAB;
    const unsigned short* k2 = ws + (size_t)(2 * NB + b) * SLAB;
    const int co = head * DHEAD;

    // ---- stage key patch: 1920 16B copies, source pre-swizzled by pos&7 ----
#pragma unroll
    for (int it = 0; it < 8; ++it) {
        const int g = it * 256 + tid;
        if (g < 2 * NPOS * 8) {
            const int row = g >> 3;            // 0..239
            const int u = g & 7;               // LDS 16B unit
            const int lm = row >= NPOS;
            const int pos = row - (lm ? NPOS : 0);
            const int pr = pos / PWC, pc = pos - pr * PWC;
            const int hh = h0 + pr - 2, wp = w0 + pc - 2;
            short8v v = {0, 0, 0, 0, 0, 0, 0, 0};
            if (hh >= 0 && hh < HH && wp >= 0 && wp < WWD) {
                const unsigned short* kmap = lm ? k2 : k1;
                v = *reinterpret_cast<const short8v*>(
                    &kmap[(size_t)(hh * WWD + wp) * OCC + co
                          + ((u ^ (pos & 7)) << 3)]);
            }
            *reinterpret_cast<short8v*>(&kp[row * 64 + u * 8]) = v;
        }
    }
    __syncthreads();

    const int e = tid & 7;            // d-eighth (8 chans)
    const int pixl = tid >> 3;        // 0..31
    const int pi = pixl >> 4, pj = pixl & 15;
    const int pix = (h0 + pi) * WWD + (w0 + pj);

    // q fragment: packed fp16 pairs, pre-scaled by 0.125*log2e (pk_mul_f16)
    half2v qs[4];
    {
        uint4 qw = *reinterpret_cast<const uint4*>(
            &qp[(size_t)pix * OCC + co + e * 8]);
        const half2v sc2 = {(_Float16)SCALE_E, (_Float16)SCALE_E};
        h2u t;
        t.u = qw.x; qs[0] = t.h * sc2;
        t.u = qw.y; qs[1] = t.h * sc2;
        t.u = qw.z; qs[2] = t.h * sc2;
        t.u = qw.w; qs[3] = t.h * sc2;
    }

    float den = 0.f;
    float acc[8];
#pragma unroll
    for (int k = 0; k < 8; ++k) acc[k] = 0.f;

#pragma unroll
    for (int r = 0; r < 25; ++r) {
        const int di = r / 5, dj = r % 5;
        const int pos = (pi + di) * PWC + (pj + dj);
        const int uoff = ((e ^ (pos & 7)) << 3);

        uint4 k1w = *reinterpret_cast<const uint4*>(&kp[pos * 64 + uoff]);
        uint4 k2w = *reinterpret_cast<const uint4*>(
            &kp[(NPOS + pos) * 64 + uoff]);

        h2u a0, a1, a2, a3, c0, c1, c2, c3;
        a0.u = k1w.x; a1.u = k1w.y; a2.u = k1w.z; a3.u = k1w.w;
        c0.u = k2w.x; c1.u = k2w.y; c2.u = k2w.z; c3.u = k2w.w;

        float s1 = 0.f, s2 = 0.f;
        s1 = __builtin_amdgcn_fdot2(a0.h, qs[0], s1, false);
        s1 = __builtin_amdgcn_fdot2(a1.h, qs[1], s1, false);
        s1 = __builtin_amdgcn_fdot2(a2.h, qs[2], s1, false);
        s1 = __builtin_amdgcn_fdot2(a3.h, qs[3], s1, false);
        s2 = __builtin_amdgcn_fdot2(c0.h, qs[0], s2, false);
        s2 = __builtin_amdgcn_fdot2(c1.h, qs[1], s2, false);
        s2 = __builtin_amdgcn_fdot2(c2.h, qs[2], s2, false);
        s2 = __builtin_amdgcn_fdot2(c3.h, qs[3], s2, false);
        s1 = xreduce8(s1);
        s2 = xreduce8(s2);

        const float p1 = exp2f(s1);
        const float p2 = exp2f(s2);
        den += p1 + p2;

        acc[0] += p1 * (float)a0.h[0] + p2 * (float)c0.h[0];
        acc[1] += p1 * (float)a0.h[1] + p2 * (float)c0.h[1];
        acc[2] += p1 * (float)a1.h[0] + p2 * (float)c1.h[0];
        acc[3] += p1 * (float)a1.h[1] + p2 * (float)c1.h[1];
        acc[4] += p1 * (float)a2.h[0] + p2 * (float)c2.h[0];
        acc[5] += p1 * (float)a2.h[1] + p2 * (float)c2.h[1];
        acc[6] += p1 * (float)a3.h[0] + p2 * (float)c3.h[0];
        acc[7] += p1 * (float)a3.h[1] + p2 * (float)c3.h[1];
    }

    const float rden = 1.f / den;

    // direct output: wave writes 8 chans x 8 consecutive pixels (32B chunks,
    // paired by the sibling wave into full 64B lines within this block)
#pragma unroll
    for (int k = 0; k < 8; ++k) {
        out[((size_t)b * OCC + co + e * 8 + k) * NPIX + pix] = acc[k] * rden;
    }
}

extern "C" void kernel_launch(void* const* d_in, const int* in_sizes, int n_in,
                              void* d_out, int out_size, void* d_ws, size_t ws_size,
                              hipStream_t stream) {
    const float* kvmap1 = (const float*)d_in[0];
    const float* qmap   = (const float*)d_in[1];
    const float* kvmap2 = (const float*)d_in[2];
    const float* Wq     = (const float*)d_in[3];
    const float* Wkv    = (const float*)d_in[4];
    float* out = (float*)d_out;
    unsigned short* ws = (unsigned short*)d_ws;
    unsigned short* wsW = ws + 6 * SLAB;   // W hi/lo bf16 (512 KB)

    prep_w<<<64, 256, 0, stream>>>(Wq, Wkv, wsW);

    dim3 ggrid(NPIX / 64, OCC / 64, 3 * NB);   // (36, 4, 6)
    proj_mfma<<<ggrid, 256, 0, stream>>>(qmap, kvmap1, kvmap2, wsW, ws);

    const int nblocks = NTILES * NHEADS * NB;   // 576
    attn_kernel<<<nblocks, 256, 0, stream>>>(ws, out);
}

// Round 16
// 34.269 us; speedup vs baseline: 1.1281x; 1.1281x over previous
//
#include <hip/hip_runtime.h>

#define HH 48
#define WWD 48
#define CC 256
#define OCC 256
#define NPIX 2304
#define NB 2
#define NHEADS 4
#define DHEAD 64
#define SCALE_E 0.1803368802f   // 0.125 * log2(e); softmax via exp2

// attention tiling: 2x16 pixel tile, 6x20 patch
#define TH 2
#define TW 16
#define PHR 6
#define PWC 20
#define NPOS 120            // PHR*PWC
#define NTILES 72           // (48/2)*(48/16)

#define SLAB ((size_t)NPIX * OCC)   // elements (fp16 ushort)

typedef __attribute__((ext_vector_type(8))) short short8v;
typedef __attribute__((ext_vector_type(4))) float floatx4;
typedef _Float16 half2v __attribute__((ext_vector_type(2)));
typedef __fp16 fp16x2 __attribute__((ext_vector_type(2)));
union h2u { unsigned u; half2v h; fp16x2 g; };

__device__ __forceinline__ unsigned short f2bf(float f) {
    union { float f; unsigned u; } v; v.f = f;
    unsigned r = v.u + 0x7FFFu + ((v.u >> 16) & 1u);   // RNE
    return (unsigned short)(r >> 16);
}
__device__ __forceinline__ float bf2f(unsigned short b) {
    union { unsigned u; float f; } v; v.u = ((unsigned)b) << 16; return v.f;
}

// 8-lane (bits 0..2) all-reduce sum: xor1/xor2 via DPP quad_perm (VALU pipe),
// xor4 via one shfl.
__device__ __forceinline__ float xreduce8(float s) {
    s += __int_as_float(__builtin_amdgcn_update_dpp(
        0, __float_as_int(s), 0xB1, 0xf, 0xf, true));   // [1,0,3,2]
    s += __int_as_float(__builtin_amdgcn_update_dpp(
        0, __float_as_int(s), 0x4E, 0xf, 0xf, true));   // [2,3,0,1]
    s += __shfl_xor(s, 4, 64);
    return s;
}

// ---------------------------------------------------------------------------
// MFMA projection — R12 structure verbatim (in-block W hi/lo conversion,
// manual-RNE B-stage; NO prep_w kernel, NO inline-asm cvt in the hot path —
// R14 lesson: asm cvt_pk in staging defeats compiler scheduling).
// ONLY change vs R12: epilogue emits FP16 slabs via the cvt_pkrtz BUILTIN
// (2 instr / 4 vals, replaces 16 manual f2bf ops; RTZ@fp16 is tighter than
// RNE@bf16 for |v|<64 so the error budget is unchanged-or-better).
// ---------------------------------------------------------------------------
__global__ __launch_bounds__(256) void proj_mfma(
    const float* __restrict__ Wq, const float* __restrict__ Wkv,
    const float* __restrict__ qmap, const float* __restrict__ kv1,
    const float* __restrict__ kv2, unsigned short* __restrict__ ws)
{
    __shared__ unsigned short Bs[64 * 64];   // 8 KB, [x][k] bf16 swizzled

    const int z = blockIdx.z;
    const int map = z % 3;
    const int b = z / 3;
    const float* Wmat = (map == 0) ? Wq : Wkv;
    const float* X = ((map == 0) ? qmap : (map == 1) ? kv1 : kv2)
                     + (size_t)b * CC * NPIX;
    unsigned short* out = ws + ((size_t)map * NB + b) * SLAB;

    const int tid = threadIdx.x;
    const int x0 = blockIdx.x * 64;
    const int o0 = blockIdx.y * 64;
    const int lane = tid & 63;
    const int wv = tid >> 6;
    const int l15 = lane & 15;
    const int l4 = lane >> 4;
    const int kq_w = tid >> 4;
    const int xq = tid & 15;

    const float* Arow = Wmat + (size_t)(o0 + wv * 16 + l15) * CC;

    floatx4 acc[4];
#pragma unroll
    for (int nt = 0; nt < 4; ++nt) acc[nt] = (floatx4){0.f, 0.f, 0.f, 0.f};

#pragma unroll
    for (int kt = 0; kt < 4; ++kt) {
        const int k0t = kt * 64;

        float4 av0 = *reinterpret_cast<const float4*>(Arow + k0t + l4 * 8);
        float4 av1 = *reinterpret_cast<const float4*>(Arow + k0t + l4 * 8 + 4);
        float4 av2 = *reinterpret_cast<const float4*>(Arow + k0t + 32 + l4 * 8);
        float4 av3 = *reinterpret_cast<const float4*>(Arow + k0t + 32 + l4 * 8 + 4);

        float4 xv[4];
#pragma unroll
        for (int i = 0; i < 4; ++i)
            xv[i] = *reinterpret_cast<const float4*>(
                &X[(size_t)(k0t + kq_w * 4 + i) * NPIX + x0 + xq * 4]);
        {
            float xt[4][4] = {
                {xv[0].x, xv[1].x, xv[2].x, xv[3].x},
                {xv[0].y, xv[1].y, xv[2].y, xv[3].y},
                {xv[0].z, xv[1].z, xv[2].z, xv[3].z},
                {xv[0].w, xv[1].w, xv[2].w, xv[3].w}};
#pragma unroll
            for (int j = 0; j < 4; ++j) {
                const int x = xq * 4 + j;
                ushort4 u;
                u.x = f2bf(xt[j][0]); u.y = f2bf(xt[j][1]);
                u.z = f2bf(xt[j][2]); u.w = f2bf(xt[j][3]);
                *reinterpret_cast<ushort4*>(
                    (char*)Bs + x * 128 + ((kq_w ^ (x & 15)) << 3)) = u;
            }
        }
        __syncthreads();

#pragma unroll
        for (int kc = 0; kc < 2; ++kc) {
            const float4 va = (kc == 0) ? av0 : av2;
            const float4 vb = (kc == 0) ? av1 : av3;
            const float a[8] = {va.x, va.y, va.z, va.w, vb.x, vb.y, vb.z, vb.w};
            short8v ah, al;
#pragma unroll
            for (int j = 0; j < 8; ++j) {
                const unsigned short h = f2bf(a[j]);
                ah[j] = (short)h;
                al[j] = (short)f2bf(a[j] - bf2f(h));
            }
#pragma unroll
            for (int nt = 0; nt < 4; ++nt) {
                const int x = nt * 16 + l15;
                const int kq = kc * 8 + l4 * 2;
                ushort4 b0 = *reinterpret_cast<ushort4*>(
                    (char*)Bs + x * 128 + ((kq ^ l15) << 3));
                ushort4 b1 = *reinterpret_cast<ushort4*>(
                    (char*)Bs + x * 128 + (((kq + 1) ^ l15) << 3));
                short8v bh;
                bh[0] = (short)b0.x; bh[1] = (short)b0.y;
                bh[2] = (short)b0.z; bh[3] = (short)b0.w;
                bh[4] = (short)b1.x; bh[5] = (short)b1.y;
                bh[6] = (short)b1.z; bh[7] = (short)b1.w;
                acc[nt] = __builtin_amdgcn_mfma_f32_16x16x32_bf16(ah, bh, acc[nt], 0, 0, 0);
                acc[nt] = __builtin_amdgcn_mfma_f32_16x16x32_bf16(al, bh, acc[nt], 0, 0, 0);
            }
        }
        __syncthreads();
    }

    // fp16 epilogue: lane covers (x, 4 consecutive o) -> one 8B store
#pragma unroll
    for (int nt = 0; nt < 4; ++nt) {
        const int x = nt * 16 + l15;
        h2u p0, p1;
        p0.g = __builtin_amdgcn_cvt_pkrtz(acc[nt][0], acc[nt][1]);
        p1.g = __builtin_amdgcn_cvt_pkrtz(acc[nt][2], acc[nt][3]);
        *reinterpret_cast<uint2*>(
            &out[(size_t)(x0 + x) * OCC + o0 + wv * 16 + l4 * 4]) =
            make_uint2(p0.u, p1.u);
    }
}

// ---------------------------------------------------------------------------
// Attention — R12 structure verbatim (256 thr, 4 waves, both maps per
// thread, plain blockIdx, direct stores, launch_bounds(256,4)).
// ONLY change vs R12: fp16 slabs consumed via v_dot2_f32_f16 (8 fdot2 vs
// 16 unpack-FMA for the two dots; unpack now feeds only the p*k accum).
// ---------------------------------------------------------------------------
__global__ __launch_bounds__(256, 4) void attn_kernel(
    const unsigned short* __restrict__ ws, float* __restrict__ out)
{
    __shared__ __align__(16) unsigned short kp[2 * NPOS * 64];   // 30720 B

    const int tid = threadIdx.x;
    const int bid = blockIdx.x;
    const int tile = bid % NTILES;
    const int head = (bid / NTILES) % NHEADS;
    const int b = bid / (NTILES * NHEADS);
    const int h0 = (tile / 3) * TH;
    const int w0 = (tile % 3) * TW;

    const unsigned short* qp = ws + (size_t)(0 * NB + b) * SLAB;
    const unsigned short* k1 = ws + (size_t)(1 * NB + b) * SLAB;
    const unsigned short* k2 = ws + (size_t)(2 * NB + b) * SLAB;
    const int co = head * DHEAD;

    // ---- stage key patch: 1920 16B copies, source pre-swizzled by pos&7 ----
#pragma unroll
    for (int it = 0; it < 8; ++it) {
        const int g = it * 256 + tid;
        if (g < 2 * NPOS * 8) {
            const int row = g >> 3;            // 0..239
            const int u = g & 7;               // LDS 16B unit
            const int lm = row >= NPOS;
            const int pos = row - (lm ? NPOS : 0);
            const int pr = pos / PWC, pc = pos - pr * PWC;
            const int hh = h0 + pr - 2, wp = w0 + pc - 2;
            short8v v = {0, 0, 0, 0, 0, 0, 0, 0};
            if (hh >= 0 && hh < HH && wp >= 0 && wp < WWD) {
                const unsigned short* kmap = lm ? k2 : k1;
                v = *reinterpret_cast<const short8v*>(
                    &kmap[(size_t)(hh * WWD + wp) * OCC + co
                          + ((u ^ (pos & 7)) << 3)]);
            }
            *reinterpret_cast<short8v*>(&kp[row * 64 + u * 8]) = v;
        }
    }
    __syncthreads();

    const int e = tid & 7;            // d-eighth (8 chans)
    const int pixl = tid >> 3;        // 0..31
    const int pi = pixl >> 4, pj = pixl & 15;
    const int pix = (h0 + pi) * WWD + (w0 + pj);

    // q fragment: packed fp16 pairs, pre-scaled by 0.125*log2e
    half2v qs[4];
    {
        uint4 qw = *reinterpret_cast<const uint4*>(
            &qp[(size_t)pix * OCC + co + e * 8]);
        const half2v sc2 = {(_Float16)SCALE_E, (_Float16)SCALE_E};
        h2u t;
        t.u = qw.x; qs[0] = t.h * sc2;
        t.u = qw.y; qs[1] = t.h * sc2;
        t.u = qw.z; qs[2] = t.h * sc2;
        t.u = qw.w; qs[3] = t.h * sc2;
    }

    float den = 0.f;
    float acc[8];
#pragma unroll
    for (int k = 0; k < 8; ++k) acc[k] = 0.f;

#pragma unroll
    for (int r = 0; r < 25; ++r) {
        const int di = r / 5, dj = r % 5;
        const int pos = (pi + di) * PWC + (pj + dj);
        const int uoff = ((e ^ (pos & 7)) << 3);

        uint4 k1w = *reinterpret_cast<const uint4*>(&kp[pos * 64 + uoff]);
        uint4 k2w = *reinterpret_cast<const uint4*>(
            &kp[(NPOS + pos) * 64 + uoff]);

        h2u a0, a1, a2, a3, c0, c1, c2, c3;
        a0.u = k1w.x; a1.u = k1w.y; a2.u = k1w.z; a3.u = k1w.w;
        c0.u = k2w.x; c1.u = k2w.y; c2.u = k2w.z; c3.u = k2w.w;

        float s1 = 0.f, s2 = 0.f;
        s1 = __builtin_amdgcn_fdot2(a0.h, qs[0], s1, false);
        s1 = __builtin_amdgcn_fdot2(a1.h, qs[1], s1, false);
        s1 = __builtin_amdgcn_fdot2(a2.h, qs[2], s1, false);
        s1 = __builtin_amdgcn_fdot2(a3.h, qs[3], s1, false);
        s2 = __builtin_amdgcn_fdot2(c0.h, qs[0], s2, false);
        s2 = __builtin_amdgcn_fdot2(c1.h, qs[1], s2, false);
        s2 = __builtin_amdgcn_fdot2(c2.h, qs[2], s2, false);
        s2 = __builtin_amdgcn_fdot2(c3.h, qs[3], s2, false);
        s1 = xreduce8(s1);
        s2 = xreduce8(s2);

        const float p1 = exp2f(s1);
        const float p2 = exp2f(s2);
        den += p1 + p2;

        acc[0] += p1 * (float)a0.h[0] + p2 * (float)c0.h[0];
        acc[1] += p1 * (float)a0.h[1] + p2 * (float)c0.h[1];
        acc[2] += p1 * (float)a1.h[0] + p2 * (float)c1.h[0];
        acc[3] += p1 * (float)a1.h[1] + p2 * (float)c1.h[1];
        acc[4] += p1 * (float)a2.h[0] + p2 * (float)c2.h[0];
        acc[5] += p1 * (float)a2.h[1] + p2 * (float)c2.h[1];
        acc[6] += p1 * (float)a3.h[0] + p2 * (float)c3.h[0];
        acc[7] += p1 * (float)a3.h[1] + p2 * (float)c3.h[1];
    }

    const float rden = 1.f / den;

    // direct output: wave writes 8 chans x 8 consecutive pixels (32B chunks,
    // paired by the sibling wave into full 64B lines within this block)
#pragma unroll
    for (int k = 0; k < 8; ++k) {
        out[((size_t)b * OCC + co + e * 8 + k) * NPIX + pix] = acc[k] * rden;
    }
}

extern "C" void kernel_launch(void* const* d_in, const int* in_sizes, int n_in,
                              void* d_out, int out_size, void* d_ws, size_t ws_size,
                              hipStream_t stream) {
    const float* kvmap1 = (const float*)d_in[0];
    const float* qmap   = (const float*)d_in[1];
    const float* kvmap2 = (const float*)d_in[2];
    const float* Wq     = (const float*)d_in[3];
    const float* Wkv    = (const float*)d_in[4];
    float* out = (float*)d_out;
    unsigned short* ws = (unsigned short*)d_ws;

    dim3 ggrid(NPIX / 64, OCC / 64, 3 * NB);   // (36, 4, 6)
    proj_mfma<<<ggrid, 256, 0, stream>>>(Wq, Wkv, qmap, kvmap1, kvmap2, ws);

    const int nblocks = NTILES * NHEADS * NB;   // 576
    attn_kernel<<<nblocks, 256, 0, stream>>>(ws, out);
}